// Round 4
// baseline (180.630 us; speedup 1.0000x reference)
//
#include <hip/hip_runtime.h>
#include <hip/hip_cooperative_groups.h>
#include <math.h>

namespace cg = cooperative_groups;

#define C_IN  128
#define H_IN  56
#define W_IN  56
#define HW_IN (H_IN * W_IN)          // 3136
#define N_IN  8
#define O_MID 64

// Weff layout (floats): rows of 52 per channel, slot = (di*5+dj)*2 + k
// (50 used, 2 pad so rows are 16B-aligned for b128 LDS reads)
#define WROW     52
#define WEFF_FL  (C_IN * WROW)        // 6656
#define BEFF_OFF WEFF_FL

// Module-scope buffers (R2 proved the 256 MiB harness poison fill runs
// regardless of d_ws use). Both fully rewritten every iteration.
__device__ __align__(16) float g_weff[WEFF_FL + 4];
__device__ __align__(16) float g_G[25 * N_IN * HW_IN * 2];   // ~5.0 MB

// ---------------- k_all: cooperative, 3 phases, 2 grid syncs ----------------
// grid dim3(8, 49): linear dispatch id = n + 8*tile -> id%8 = n, so all blocks
// of batch n land on one XCD; x[n] (1.6 MB) is L2-resident and G[n] (627 KB)
// stays in that XCD's L2 between phase B and phase C.
// R4 change vs R2: SAME three phases, but one dispatch instead of three
// (R1-calibrated boundary cost ~6 us each; grid.sync ~2-4 us each).
// Halo fusion abandoned (R3 post-mortem: 2.25x GEMM work >> saved round-trip).
__global__ __launch_bounds__(256) void k_all(const float* __restrict__ x,
                                             const float* __restrict__ Wt,
                                             const float* __restrict__ bias,
                                             const float* __restrict__ Wlin,
                                             const float* __restrict__ blin,
                                             float* __restrict__ out) {
    __shared__ float wls[WEFF_FL + 4];    // 26640 B: Weff rows + beff

    const int tid  = threadIdx.x;
    const int n    = blockIdx.x;
    const int tile = blockIdx.y;
    const int bid  = n + 8 * tile;        // linear dispatch id

    // ---- phase A: weff fold of O=64 (blocks 0..12 only; others just sync) ----
    // Full o-unroll: 64 independent Wt loads in flight -> one vmcnt wait.
    const int e = bid * 256 + tid;
    if (e < 3200) {
        float a0 = 0.f, a1 = 0.f;
#pragma unroll
        for (int o = 0; o < O_MID; ++o) {
            const float wt = Wt[o * 3200 + e];
            a0 = fmaf(Wlin[o], wt, a0);
            a1 = fmaf(Wlin[64 + o], wt, a1);
        }
        const int c = e / 25;
        const int p = e - c * 25;
        g_weff[c * WROW + p * 2 + 0] = a0;
        g_weff[c * WROW + p * 2 + 1] = a1;
    }
    if (bid == 12 && tid >= 128 && tid < 192) {
        const int o = tid - 128;
        float v0 = Wlin[o] * bias[o];
        float v1 = Wlin[64 + o] * bias[o];
#pragma unroll
        for (int off = 32; off; off >>= 1) {
            v0 += __shfl_down(v0, off, 64);
            v1 += __shfl_down(v1, off, 64);
        }
        if (o == 0) {
            g_weff[BEFF_OFF + 0] = v0 + blin[0];
            g_weff[BEFF_OFF + 1] = v1 + blin[1];
        }
    }

    cg::this_grid().sync();

    // ---- phase B: GEMM, R2 k_gemm structure verbatim (proven fastest) ----
    // Wave wv covers px [wv*16, wv*16+16); lane = cgrp*16+px; c = s*4+cgrp.
    // All 32 x-loads issued before the FMA loop (one latency, not 32).
#pragma unroll
    for (int r = 0; r < 7; ++r) {
        const int i4 = tid + 256 * r;     // float4 index, 1665 total (incl beff)
        if (i4 < 1665)
            *(float4*)&wls[i4 * 4] = *(const float4*)&g_weff[i4 * 4];
    }
    __syncthreads();

    const int wv   = tid >> 6;
    const int lane = tid & 63;
    const int cgrp = lane >> 4;
    const int px   = lane & 15;
    const int hw   = tile * 64 + wv * 16 + px;

    {
        const float* xc = x + (size_t)n * (C_IN * HW_IN) + hw;

        float xv[32];
#pragma unroll
        for (int s = 0; s < 32; ++s)
            xv[s] = xc[(size_t)(s * 4 + cgrp) * HW_IN];

        float acc[50];
#pragma unroll
        for (int i = 0; i < 50; ++i) acc[i] = 0.f;

#pragma unroll
        for (int s = 0; s < 32; ++s) {
            const float* wr = &wls[(s * 4 + cgrp) * WROW];
#pragma unroll
            for (int i = 0; i < 50; ++i)
                acc[i] = fmaf(xv[s], wr[i], acc[i]);
        }

        // reduce across cgrp (lane bits 4,5)
#pragma unroll
        for (int i = 0; i < 50; ++i) {
            float v = acc[i];
            v += __shfl_xor(v, 16, 64);
            v += __shfl_xor(v, 32, 64);
            acc[i] = v;
        }

        // NOTE (R13 lesson): keep exec-masked cgrp==0 stores — each store is one
        // contiguous 128B segment (16 lanes x float2).
        if (cgrp == 0) {
#pragma unroll
            for (int p = 0; p < 25; ++p) {
                const size_t idx = (((size_t)p * N_IN + n) * HW_IN + hw) * 2;
                *(float2*)&g_G[idx] = make_float2(acc[p * 2 + 0], acc[p * 2 + 1]);
            }
        }
    }

    cg::this_grid().sync();

    // ---- phase C: final stats, R2 k_final structure verbatim ----
    // 25 gathers issued up front (clamped addr, masked after) -> one latency.
    if (tid < 128) {
        const int fpx = tid >> 1;
        const int k   = tid & 1;
        const int fhw = tile * 64 + fpx;
        const int y   = fhw / W_IN;
        const int xx0 = fhw - y * W_IN;

        const float be = wls[BEFF_OFF + k];

        float vbuf[25];
        bool  okm[25];
#pragma unroll
        for (int di = 0; di < 5; ++di) {
            const int yy = y + di - 2;
#pragma unroll
            for (int dj = 0; dj < 5; ++dj) {
                const int xx = xx0 + dj - 2;
                const int p  = di * 5 + dj;
                const bool ok = ((unsigned)yy < H_IN) && ((unsigned)xx < W_IN);
                const size_t idx = ok
                    ? ((((size_t)p * N_IN + n) * HW_IN + yy * W_IN + xx) * 2 + k)
                    : (size_t)0;
                vbuf[p] = g_G[idx];       // independent loads, all in flight
                okm[p]  = ok;
            }
        }

        float A = 0.f, X = 0.f, Y = 0.f, Cs = 0.f;
#pragma unroll
        for (int di = 0; di < 5; ++di) {
            const float fdi = (float)(di - 2);
#pragma unroll
            for (int dj = 0; dj < 5; ++dj) {
                const int p = di * 5 + dj;
                const float v = (okm[p] ? vbuf[p] : 0.f) + be;
                const float a = fabsf(v);
                A += a;
                X  = fmaf(a, (float)(dj - 2), X);
                Y  = fmaf(a, fdi, Y);
                Cs += v;
            }
        }

        const float xd = X / A, yd = Y / A;
        const float o = Cs * expf(-0.5f * sqrtf(xd * xd + yd * yd));
        out[((size_t)n * HW_IN + fhw) * 2 + k] = o;
    }
}

extern "C" void kernel_launch(void* const* d_in, const int* in_sizes, int n_in,
                              void* d_out, int out_size, void* d_ws, size_t ws_size,
                              hipStream_t stream) {
    const float* x    = (const float*)d_in[0];
    const float* Wt   = (const float*)d_in[1];
    const float* bias = (const float*)d_in[2];
    const float* Wlin = (const float*)d_in[3];
    const float* blin = (const float*)d_in[4];
    float* out = (float*)d_out;
    (void)d_ws; (void)ws_size;

    void* args[] = {(void*)&x, (void*)&Wt, (void*)&bias,
                    (void*)&Wlin, (void*)&blin, (void*)&out};
    hipLaunchCooperativeKernel((const void*)k_all, dim3(8, 49), dim3(256),
                               args, 0, stream);
}